// Round 1
// baseline (2677.895 us; speedup 1.0000x reference)
//
#include <hip/hip_runtime.h>
#include <hip/hip_bf16.h>

// COO SpMM: out[row[e], :] += ev[e] * x[col[e], :]
// N=100000 nodes, E=1600000 edges, D=128 fp32 features.
// Layout: 32 threads per edge; each thread owns one float4 (4 features).
// Gather of x[col] is fully coalesced (512 B contiguous per edge).
// Scatter uses HW fp32 atomics (unsafeAtomicAdd -> global_atomic_add_f32).

#define D_FEAT 128
#define LANES_PER_EDGE 32   // 128 feats / 4 per float4

__global__ __launch_bounds__(256) void spmm_scatter_kernel(
    const float* __restrict__ x,
    const int* __restrict__ edge_index,   // [2, E] flattened: row=ei[e], col=ei[E+e]
    const float* __restrict__ edge_values,
    float* __restrict__ out,
    int E) {
    long long t = (long long)blockIdx.x * blockDim.x + threadIdx.x;
    int e = (int)(t >> 5);          // edge id
    int part = (int)(t & 31);       // which float4 of the 128-feat row
    if (e >= E) return;

    int row = edge_index[e];
    int col = edge_index[E + e];
    float w = edge_values[e];

    const float4* xrow = reinterpret_cast<const float4*>(x + (size_t)col * D_FEAT);
    float4 v = xrow[part];

    float* o = out + (size_t)row * D_FEAT + part * 4;
    unsafeAtomicAdd(o + 0, v.x * w);
    unsafeAtomicAdd(o + 1, v.y * w);
    unsafeAtomicAdd(o + 2, v.z * w);
    unsafeAtomicAdd(o + 3, v.w * w);
}

extern "C" void kernel_launch(void* const* d_in, const int* in_sizes, int n_in,
                              void* d_out, int out_size, void* d_ws, size_t ws_size,
                              hipStream_t stream) {
    const float* x           = (const float*)d_in[0];
    const int*   edge_index  = (const int*)d_in[1];
    const float* edge_values = (const float*)d_in[2];
    float*       out         = (float*)d_out;

    int E = in_sizes[2];  // edge_values has E elements

    // d_out is poisoned (0xAA) before timing and never re-poisoned between
    // replays; we accumulate into it, so zero it every call (deterministic).
    hipMemsetAsync(d_out, 0, (size_t)out_size * sizeof(float), stream);

    long long total_threads = (long long)E * LANES_PER_EDGE;
    int block = 256;
    long long grid = (total_threads + block - 1) / block;
    spmm_scatter_kernel<<<(dim3)(unsigned)grid, block, 0, stream>>>(
        x, edge_index, edge_values, out, E);
}

// Round 2
// 323.202 us; speedup vs baseline: 8.2855x; 8.2855x over previous
//
#include <hip/hip_runtime.h>
#include <hip/hip_bf16.h>

// COO SpMM: out[row[e], :] += ev[e] * x[col[e], :]
// N=100000, E=1600000, D=128 fp32.
//
// Strategy: build CSR per call (counting sort in d_ws), then one wave (64
// lanes) per output row gathers+accumulates its edges in registers and writes
// the row exactly once. No fp atomics -> write traffic drops 3.2GB -> ~64MB.

#define D_FEAT 128

// ---------------- phase kernels ----------------

__global__ __launch_bounds__(256) void hist_kernel(
    const int* __restrict__ rows, int* __restrict__ counts, int E) {
    int i = blockIdx.x * 256 + threadIdx.x;
    if (i < E) atomicAdd(&counts[rows[i]], 1);
}

// Block-local exclusive scan (in place over counts->start) + per-block totals.
__global__ __launch_bounds__(256) void scan1_kernel(
    int* __restrict__ start, int* __restrict__ bsums, int n) {
    __shared__ int tmp[256];
    int tid = threadIdx.x;
    int i = blockIdx.x * 256 + tid;
    int v = (i < n) ? start[i] : 0;
    tmp[tid] = v;
    __syncthreads();
    for (int off = 1; off < 256; off <<= 1) {
        int t = (tid >= off) ? tmp[tid - off] : 0;
        __syncthreads();
        tmp[tid] += t;
        __syncthreads();
    }
    if (i < n) start[i] = tmp[tid] - v;   // exclusive
    if (tid == 255) bsums[blockIdx.x] = tmp[255];
}

// Single-block exclusive scan of block sums (nb <= 512).
__global__ __launch_bounds__(512) void scan2_kernel(int* __restrict__ bsums, int nb) {
    __shared__ int tmp[512];
    int tid = threadIdx.x;
    int v = (tid < nb) ? bsums[tid] : 0;
    tmp[tid] = v;
    __syncthreads();
    for (int off = 1; off < 512; off <<= 1) {
        int t = (tid >= off) ? tmp[tid - off] : 0;
        __syncthreads();
        tmp[tid] += t;
        __syncthreads();
    }
    if (tid < nb) bsums[tid] = tmp[tid] - v;
}

// Add block offsets; init cursor; set start[n] = E.
__global__ __launch_bounds__(256) void scan3_kernel(
    int* __restrict__ start, const int* __restrict__ bsums,
    int* __restrict__ cursor, int n, int E) {
    int i = blockIdx.x * 256 + threadIdx.x;
    if (i < n) {
        int s = start[i] + bsums[blockIdx.x];
        start[i] = s;
        cursor[i] = s;
    }
    if (i == 0) start[n] = E;
}

// Scatter edges into row-sorted packed (col, w) pairs.
__global__ __launch_bounds__(256) void scatter_kernel(
    const int* __restrict__ rows, const int* __restrict__ cols,
    const float* __restrict__ w, int* __restrict__ cursor,
    int2* __restrict__ packed, int E) {
    int i = blockIdx.x * 256 + threadIdx.x;
    if (i >= E) return;
    int r = rows[i];
    int p = atomicAdd(&cursor[r], 1);
    int2 cw;
    cw.x = cols[i];
    cw.y = __float_as_int(w[i]);
    packed[p] = cw;
}

// One wave per row: gather x[col] (float2/lane) and accumulate in registers.
__global__ __launch_bounds__(256) void spmm_csr_kernel(
    const float* __restrict__ x, const int* __restrict__ start,
    const int2* __restrict__ packed, float* __restrict__ out, int N) {
    int wid = (int)((blockIdx.x * 256 + threadIdx.x) >> 6);  // global wave id = row
    int lane = threadIdx.x & 63;
    if (wid >= N) return;

    int s = start[wid];
    int t = start[wid + 1];
    const float2* x2 = reinterpret_cast<const float2*>(x);
    float2 acc = make_float2(0.f, 0.f);

    int e = s;
    for (; e + 1 < t; e += 2) {
        int2 cw0 = packed[e];
        int2 cw1 = packed[e + 1];
        float2 v0 = x2[(size_t)cw0.x * 64 + lane];
        float2 v1 = x2[(size_t)cw1.x * 64 + lane];
        float w0 = __int_as_float(cw0.y);
        float w1 = __int_as_float(cw1.y);
        acc.x += w0 * v0.x;
        acc.y += w0 * v0.y;
        acc.x += w1 * v1.x;
        acc.y += w1 * v1.y;
    }
    if (e < t) {
        int2 cw = packed[e];
        float2 v = x2[(size_t)cw.x * 64 + lane];
        float w0 = __int_as_float(cw.y);
        acc.x += w0 * v.x;
        acc.y += w0 * v.y;
    }
    reinterpret_cast<float2*>(out)[(size_t)wid * 64 + lane] = acc;
}

// ---------------- fallback (round-1 atomic path) ----------------

__global__ __launch_bounds__(256) void spmm_scatter_kernel(
    const float* __restrict__ x, const int* __restrict__ edge_index,
    const float* __restrict__ edge_values, float* __restrict__ out, int E) {
    long long t = (long long)blockIdx.x * blockDim.x + threadIdx.x;
    int e = (int)(t >> 5);
    int part = (int)(t & 31);
    if (e >= E) return;
    int row = edge_index[e];
    int col = edge_index[E + e];
    float w = edge_values[e];
    const float4* xrow = reinterpret_cast<const float4*>(x + (size_t)col * D_FEAT);
    float4 v = xrow[part];
    float* o = out + (size_t)row * D_FEAT + part * 4;
    unsafeAtomicAdd(o + 0, v.x * w);
    unsafeAtomicAdd(o + 1, v.y * w);
    unsafeAtomicAdd(o + 2, v.z * w);
    unsafeAtomicAdd(o + 3, v.w * w);
}

// ---------------- launch ----------------

extern "C" void kernel_launch(void* const* d_in, const int* in_sizes, int n_in,
                              void* d_out, int out_size, void* d_ws, size_t ws_size,
                              hipStream_t stream) {
    const float* x           = (const float*)d_in[0];
    const int*   edge_index  = (const int*)d_in[1];
    const float* edge_values = (const float*)d_in[2];
    float*       out         = (float*)d_out;

    int E = in_sizes[2];
    int N = out_size / D_FEAT;

    const int* rows = edge_index;
    const int* cols = edge_index + E;

    // workspace layout
    size_t off = 0;
    int* start  = (int*)((char*)d_ws + off); off += (size_t)(N + 1) * sizeof(int);
    int* cursor = (int*)((char*)d_ws + off); off += (size_t)N * sizeof(int);
    int nb = (N + 255) / 256;
    int* bsums  = (int*)((char*)d_ws + off); off += (size_t)nb * sizeof(int);
    off = (off + 15) & ~(size_t)15;  // align packed to 16B
    int2* packed = (int2*)((char*)d_ws + off); off += (size_t)E * sizeof(int2);

    if (off > ws_size || nb > 512) {
        // fallback: atomic scatter
        hipMemsetAsync(d_out, 0, (size_t)out_size * sizeof(float), stream);
        long long total_threads = (long long)E * 32;
        int block = 256;
        long long grid = (total_threads + block - 1) / block;
        spmm_scatter_kernel<<<(dim3)(unsigned)grid, block, 0, stream>>>(
            x, edge_index, edge_values, out, E);
        return;
    }

    // 1) zero histogram
    hipMemsetAsync(start, 0, (size_t)(N + 1) * sizeof(int), stream);
    // 2) histogram of rows
    int ebl = (E + 255) / 256;
    hist_kernel<<<ebl, 256, 0, stream>>>(rows, start, E);
    // 3) exclusive scan -> start offsets, cursor copy
    scan1_kernel<<<nb, 256, 0, stream>>>(start, bsums, N);
    scan2_kernel<<<1, 512, 0, stream>>>(bsums, nb);
    scan3_kernel<<<nb, 256, 0, stream>>>(start, bsums, cursor, N, E);
    // 4) scatter edges into row-sorted packed array
    scatter_kernel<<<ebl, 256, 0, stream>>>(rows, cols, edge_values, cursor, packed, E);
    // 5) gather-accumulate, one wave per row, single write per output row
    int waves = N;
    int blocks = (waves * 64 + 255) / 256;
    spmm_csr_kernel<<<blocks, 256, 0, stream>>>(x, start, packed, out, N);
}